// Round 8
// baseline (1253.932 us; speedup 1.0000x reference)
//
#include <hip/hip_runtime.h>
#include <math.h>

constexpr int kNodes = 50000;
constexpr int kEdges = 600000;
constexpr float kAlpha = 0.2f;
constexpr float kNegBig = -1e30f;

constexpr int kGrid  = 1024;   // exactly 4 blocks/CU * 256 CUs — all co-resident
constexpr int kBlock = 256;

constexpr int kScanChunk  = 1024;
constexpr int kScanBlocks = (kNodes + kScanChunk - 1) / kScanChunk; // 49

// ws layout (4-byte units):
// [0]=barrier count  [1]=barrier gen  [2..4) pad   (memset to 0 with counts)
constexpr int kOffCounts   = 4;
constexpr int kOffOffsets  = kOffCounts + kNodes;    // 50004
constexpr int kOffCursor   = kOffOffsets + kNodes;   // 100004
constexpr int kOffCsrD     = kOffCursor + kNodes;    // 150004
constexpr int kOffMnode    = kOffCsrD + kEdges;      // 750004
constexpr int kOffBlockSum = kOffMnode + kNodes;     // 800004 (+49)
constexpr int kOffPartials = kOffBlockSum + 50;      // 800054 even -> float2 8B-aligned ✓

__device__ __forceinline__ void onlineMerge(float& m, float& s, float m2, float s2) {
    const float M = fmaxf(m, m2);
    s = s * expf(m - M) + s2 * expf(m2 - M);
    m = M;
}

// Software grid barrier. Requires all kGrid blocks co-resident (guaranteed by
// launch_bounds(256,4) and grid == 4*256 CUs). Device-scope atomics are
// XCD-coherent; __threadfence() flushes/invalidates L2 for the plain
// stores/loads that cross the barrier.
__device__ __forceinline__ void gridBarrier(int* cnt, int* gen) {
    __threadfence();               // release: my phase-N writes visible device-wide
    __syncthreads();
    if (threadIdx.x == 0) {
        const int g = __hip_atomic_load(gen, __ATOMIC_RELAXED, __HIP_MEMORY_SCOPE_AGENT);
        if (__hip_atomic_fetch_add(cnt, 1, __ATOMIC_ACQ_REL, __HIP_MEMORY_SCOPE_AGENT) == kGrid - 1) {
            __hip_atomic_store(cnt, 0, __ATOMIC_RELAXED, __HIP_MEMORY_SCOPE_AGENT);
            __hip_atomic_fetch_add(gen, 1, __ATOMIC_ACQ_REL, __HIP_MEMORY_SCOPE_AGENT);
        } else {
            while (__hip_atomic_load(gen, __ATOMIC_RELAXED, __HIP_MEMORY_SCOPE_AGENT) == g) {}
        }
    }
    __syncthreads();
    __threadfence();               // acquire: don't read stale lines
}

__global__ __launch_bounds__(kBlock, 4)
void fused_mega(const float4* __restrict__ emb4,
                const int2* __restrict__ rel2,
                int* __restrict__ wsi,
                float4* __restrict__ out4) {
    int*    cnt      = wsi;
    int*    gen      = wsi + 1;
    int*    counts   = wsi + kOffCounts;
    int*    offsets  = wsi + kOffOffsets;
    int*    cursor   = wsi + kOffCursor;
    int*    csrD     = wsi + kOffCsrD;
    float*  mnode    = (float*)(wsi + kOffMnode);
    int*    blocksum = wsi + kOffBlockSum;
    float2* partials = (float2*)(wsi + kOffPartials);

    const int tid  = blockIdx.x * kBlock + threadIdx.x;
    const int nthr = kGrid * kBlock;

    __shared__ float sm[kBlock];
    __shared__ float ss[kBlock];
    __shared__ int   sredi[kBlock];
    __shared__ int   boff[kScanBlocks];
    __shared__ int   waveSum[4];
    __shared__ int   waveOff[4];

    // ---- Phase 1: histogram (counts pre-zeroed by host memset) ----------------
    for (int e = tid; e < kEdges; e += nthr)
        atomicAdd(&counts[rel2[e].x], 1);
    gridBarrier(cnt, gen);

    // ---- Phase 2a: per-chunk sums (blocks 0..48) ------------------------------
    if (blockIdx.x < kScanBlocks) {
        const int base = blockIdx.x * kScanChunk;
        int acc = 0;
        #pragma unroll
        for (int j = 0; j < 4; ++j) {
            const int i = base + 4 * (int)threadIdx.x + j;
            if (i < kNodes) acc += counts[i];
        }
        sredi[threadIdx.x] = acc;
        __syncthreads();
        for (int s = kBlock >> 1; s > 0; s >>= 1) {
            if ((int)threadIdx.x < s) sredi[threadIdx.x] += sredi[threadIdx.x + s];
            __syncthreads();
        }
        if (threadIdx.x == 0) blocksum[blockIdx.x] = sredi[0];
    }
    gridBarrier(cnt, gen);

    // ---- Phase 2b: exclusive scan -> offsets/cursor ---------------------------
    if (blockIdx.x < kScanBlocks) {
        if ((int)threadIdx.x < kScanBlocks) boff[threadIdx.x] = blocksum[threadIdx.x];
        __syncthreads();
        if (threadIdx.x == 0) {
            int run = 0;
            for (int i = 0; i < kScanBlocks; ++i) { int t = boff[i]; boff[i] = run; run += t; }
        }
        __syncthreads();
        const int base = blockIdx.x * kScanChunk;
        const int lane = threadIdx.x & 63;
        const int wave = threadIdx.x >> 6;
        int c[4];
        int sum4 = 0;
        #pragma unroll
        for (int j = 0; j < 4; ++j) {
            const int i = base + 4 * (int)threadIdx.x + j;
            c[j] = (i < kNodes) ? counts[i] : 0;
            sum4 += c[j];
        }
        int incl = sum4;
        #pragma unroll
        for (int off = 1; off < 64; off <<= 1) {
            int v = __shfl_up(incl, off);
            if (lane >= off) incl += v;
        }
        if (lane == 63) waveSum[wave] = incl;
        __syncthreads();
        if (threadIdx.x == 0) {
            int run = 0;
            for (int w = 0; w < 4; ++w) { int t = waveSum[w]; waveOff[w] = run; run += t; }
        }
        __syncthreads();
        int excl = boff[blockIdx.x] + waveOff[wave] + (incl - sum4);
        #pragma unroll
        for (int j = 0; j < 4; ++j) {
            const int i = base + 4 * (int)threadIdx.x + j;
            if (i < kNodes) { offsets[i] = excl; cursor[i] = excl; }
            excl += c[j];
        }
    }
    gridBarrier(cnt, gen);

    // ---- Phase 3: fill CSR dst list -------------------------------------------
    for (int e = tid; e < kEdges; e += nthr) {
        const int2 sd = rel2[e];
        const int pos = atomicAdd(&cursor[sd.x], 1);
        csrD[pos] = sd.y;
    }
    gridBarrier(cnt, gen);

    // ---- Phase 4: fused scores + online-softmax accumulate (fp32) -------------
    {
        const int g    = threadIdx.x & 31;
        const int grp  = tid >> 5;
        const int ngrp = nthr >> 5;
        float Mt = kNegBig, St = 0.0f;
        for (int node = grp; node < kNodes; node += ngrp) {
            const float4 a = emb4[(long long)node * 32 + g];
            float4 acc = make_float4(0.f, 0.f, 0.f, 0.f);
            float m_run = kNegBig, s_run = 0.0f;
            const int off = offsets[node];
            const int end = off + counts[node];
            int k = off;
            for (; k + 1 < end; k += 2) {
                const int d0 = csrD[k], d1 = csrD[k + 1];
                const float4 b0 = emb4[(long long)d0 * 32 + g];
                const float4 b1 = emb4[(long long)d1 * 32 + g];
                float p0 = a.x*b0.x + a.y*b0.y + a.z*b0.z + a.w*b0.w;
                float p1 = a.x*b1.x + a.y*b1.y + a.z*b1.z + a.w*b1.w;
                #pragma unroll
                for (int o = 16; o > 0; o >>= 1) { p0 += __shfl_xor(p0, o); p1 += __shfl_xor(p1, o); }
                const float s0 = p0 > 0.f ? p0 : kAlpha * p0;
                const float s1 = p1 > 0.f ? p1 : kAlpha * p1;
                const float newM = fmaxf(m_run, fmaxf(s0, s1));
                const float rs = expf(m_run - newM);
                const float w0 = expf(s0 - newM);
                const float w1 = expf(s1 - newM);
                s_run = s_run * rs + w0 + w1;
                acc.x = acc.x * rs + w0*b0.x + w1*b1.x;
                acc.y = acc.y * rs + w0*b0.y + w1*b1.y;
                acc.z = acc.z * rs + w0*b0.z + w1*b1.z;
                acc.w = acc.w * rs + w0*b0.w + w1*b1.w;
                m_run = newM;
            }
            if (k < end) {
                const int d0 = csrD[k];
                const float4 b0 = emb4[(long long)d0 * 32 + g];
                float p0 = a.x*b0.x + a.y*b0.y + a.z*b0.z + a.w*b0.w;
                #pragma unroll
                for (int o = 16; o > 0; o >>= 1) p0 += __shfl_xor(p0, o);
                const float s0 = p0 > 0.f ? p0 : kAlpha * p0;
                const float newM = fmaxf(m_run, s0);
                const float rs = expf(m_run - newM);
                const float w0 = expf(s0 - newM);
                s_run = s_run * rs + w0;
                acc.x = acc.x * rs + w0*b0.x;
                acc.y = acc.y * rs + w0*b0.y;
                acc.z = acc.z * rs + w0*b0.z;
                acc.w = acc.w * rs + w0*b0.w;
                m_run = newM;
            }
            out4[(long long)node * 32 + g] = acc;   // unnormalized
            if (g == 0) mnode[node] = m_run;
            onlineMerge(Mt, St, m_run, s_run);
        }
        if ((threadIdx.x & 31) == 0) { sm[threadIdx.x >> 5] = Mt; ss[threadIdx.x >> 5] = St; }
        __syncthreads();
        if (threadIdx.x == 0) {
            float M = sm[0], S = ss[0];
            #pragma unroll
            for (int i = 1; i < 8; ++i) onlineMerge(M, S, sm[i], ss[i]);
            partials[blockIdx.x] = make_float2(M, S);
        }
    }
    gridBarrier(cnt, gen);

    // ---- Phase 5: redundant per-block finalize (deterministic) + epilogue -----
    {
        // every block reduces all 1024 partials in the SAME order -> identical M,S
        float Mt = kNegBig, St = 0.0f;
        #pragma unroll
        for (int j = 0; j < kGrid / kBlock; ++j) {
            const float2 p = partials[j * kBlock + threadIdx.x];
            onlineMerge(Mt, St, p.x, p.y);
        }
        sm[threadIdx.x] = Mt; ss[threadIdx.x] = St;
        __syncthreads();
        for (int s = kBlock >> 1; s > 0; s >>= 1) {
            if ((int)threadIdx.x < s) {
                float m1 = sm[threadIdx.x], s1 = ss[threadIdx.x];
                onlineMerge(m1, s1, sm[threadIdx.x + s], ss[threadIdx.x + s]);
                sm[threadIdx.x] = m1; ss[threadIdx.x] = s1;
            }
            __syncthreads();
        }
        const float M    = sm[0];
        const float invS = 1.0f / ss[0];

        for (int i = tid; i < kNodes * 32; i += nthr) {
            const int node = i >> 5;
            const float scale = expf(mnode[node] - M) * invS;
            const float4 o = out4[i];
            const float4 e = emb4[i];
            out4[i] = make_float4(e.x + scale * o.x, e.y + scale * o.y,
                                  e.z + scale * o.z, e.w + scale * o.w);
        }
    }
}

extern "C" void kernel_launch(void* const* d_in, const int* in_sizes, int n_in,
                              void* d_out, int out_size, void* d_ws, size_t ws_size,
                              hipStream_t stream) {
    const float4* emb4 = (const float4*)d_in[0];
    const int2*   rel2 = (const int2*)d_in[1];
    float4* out4 = (float4*)d_out;
    int*    wsi  = (int*)d_ws;

    // zero barrier scalars + pad + counts in one memset
    hipMemsetAsync(wsi, 0, (size_t)(kOffCounts + kNodes) * sizeof(int), stream);
    hipLaunchKernelGGL(fused_mega, dim3(kGrid), dim3(kBlock), 0, stream,
                       emb4, rel2, wsi, out4);
}

// Round 9
// 1187.233 us; speedup vs baseline: 1.0562x; 1.0562x over previous
//
#include <hip/hip_runtime.h>
#include <math.h>

constexpr int kNodes = 50000;
constexpr int kEdges = 600000;
constexpr float kAlpha = 0.2f;
constexpr float kNegBig = -1e30f;

// ws layout (4-byte units):
// [0]=done1 (hist) [1]=done2 (scores) [2]=M [3]=invS  — zeroed with counts
constexpr int kOffDone1    = 0;
constexpr int kOffDone2    = 1;
constexpr int kOffM        = 2;
constexpr int kOffInvS     = 3;
constexpr int kOffCounts   = 4;
constexpr int kOffOffsets  = kOffCounts + kNodes;    // 50004
constexpr int kOffCursor   = kOffOffsets + kNodes;   // 100004
constexpr int kOffCsrD     = kOffCursor + kNodes;    // 150004
constexpr int kOffMnode    = kOffCsrD + kEdges;      // 750004
constexpr int kOffPartials = kOffMnode + kNodes;     // 800004 (even -> float2 8B aligned)

constexpr int kHistBlock = 1024;
constexpr int kHistGrid  = 586;                       // ceil(600000/1024)
constexpr int kPerThread = 49;                        // 1024*49 = 50176 >= 50000

constexpr int kNodesPerBlock = 8;                     // 256 thr / 32 lanes-per-node
constexpr int kNodeBlocks = kNodes / kNodesPerBlock;  // 6250 exactly

__device__ __forceinline__ void onlineMerge(float& m, float& s, float m2, float s2) {
    const float M = fmaxf(m, m2);
    s = s * __expf(m - M) + s2 * __expf(m2 - M);
    m = M;
}

// Phase 1+2: histogram, then the LAST block (completion counter, no waiting)
// scans all counts -> offsets & cursor.
__global__ __launch_bounds__(kHistBlock)
void hist_scan_kernel(const int2* __restrict__ rel2, int* __restrict__ wsi) {
    int* done    = wsi + kOffDone1;
    int* counts  = wsi + kOffCounts;
    int* offsets = wsi + kOffOffsets;
    int* cursor  = wsi + kOffCursor;

    const int tid = blockIdx.x * kHistBlock + threadIdx.x;
    for (int e = tid; e < kEdges; e += kHistGrid * kHistBlock)
        atomicAdd(&counts[rel2[e].x], 1);

    __threadfence();
    __shared__ int isLast;
    if (threadIdx.x == 0) isLast = (atomicAdd(done, 1) == kHistGrid - 1);
    __syncthreads();
    if (!isLast) return;
    __threadfence();

    // last block: exclusive scan of 50000 counts (49 elems/thread + block scan)
    const int base = (int)threadIdx.x * kPerThread;
    int sum = 0;
    for (int j = 0; j < kPerThread; ++j) {
        const int i = base + j;
        if (i < kNodes) sum += counts[i];
    }
    const int lane = threadIdx.x & 63;
    const int wv   = threadIdx.x >> 6;   // 16 waves
    int incl = sum;
    #pragma unroll
    for (int o = 1; o < 64; o <<= 1) {
        int v = __shfl_up(incl, o);
        if (lane >= o) incl += v;
    }
    __shared__ int wsum[16], woff[16];
    if (lane == 63) wsum[wv] = incl;
    __syncthreads();
    if (threadIdx.x == 0) {
        int run = 0;
        for (int w = 0; w < 16; ++w) { int t = wsum[w]; woff[w] = run; run += t; }
    }
    __syncthreads();
    int excl = woff[wv] + (incl - sum);
    for (int j = 0; j < kPerThread; ++j) {
        const int i = base + j;
        if (i < kNodes) {
            const int c = counts[i];
            offsets[i] = excl;
            cursor[i]  = excl;
            excl += c;
        }
    }
}

// Phase 3: fill CSR dst list.
__global__ __launch_bounds__(256)
void fillsd_kernel(const int2* __restrict__ rel2,
                   int* __restrict__ cursor,
                   int* __restrict__ csrD) {
    for (int e = blockIdx.x * blockDim.x + threadIdx.x; e < kEdges; e += gridDim.x * blockDim.x) {
        const int2 sd = rel2[e];
        const int pos = atomicAdd(&cursor[sd.x], 1);
        csrD[pos] = sd.y;
    }
}

// Phase 4: fused scores + online-softmax accumulate; last block finalizes (M, 1/S).
__global__ __launch_bounds__(256)
void scores_fused_kernel(const float4* __restrict__ emb4,
                         const int* __restrict__ offsets,
                         const int* __restrict__ counts,
                         const int* __restrict__ csrD,
                         int* __restrict__ wsi,
                         float4* __restrict__ out4) {
    float*  wsf      = (float*)wsi;
    int*    done2    = wsi + kOffDone2;
    float*  mnode    = (float*)(wsi + kOffMnode);
    float2* partials = (float2*)(wsi + kOffPartials);

    const int g   = threadIdx.x & 31;
    const int grp = threadIdx.x >> 5;
    const int node = blockIdx.x * kNodesPerBlock + grp;   // < kNodes always

    const float4 a = emb4[(long long)node * 32 + g];
    float4 acc = make_float4(0.f, 0.f, 0.f, 0.f);
    float m_run = kNegBig, s_run = 0.0f;

    const int off = offsets[node];
    const int end = off + counts[node];
    int k = off;
    for (; k + 3 < end; k += 4) {
        const int d0 = csrD[k], d1 = csrD[k+1], d2 = csrD[k+2], d3 = csrD[k+3];
        const float4 b0 = emb4[(long long)d0 * 32 + g];
        const float4 b1 = emb4[(long long)d1 * 32 + g];
        const float4 b2 = emb4[(long long)d2 * 32 + g];
        const float4 b3 = emb4[(long long)d3 * 32 + g];
        float p0 = a.x*b0.x + a.y*b0.y + a.z*b0.z + a.w*b0.w;
        float p1 = a.x*b1.x + a.y*b1.y + a.z*b1.z + a.w*b1.w;
        float p2 = a.x*b2.x + a.y*b2.y + a.z*b2.z + a.w*b2.w;
        float p3 = a.x*b3.x + a.y*b3.y + a.z*b3.z + a.w*b3.w;
        #pragma unroll
        for (int o = 16; o > 0; o >>= 1) {
            p0 += __shfl_xor(p0, o); p1 += __shfl_xor(p1, o);
            p2 += __shfl_xor(p2, o); p3 += __shfl_xor(p3, o);
        }
        const float s0 = p0 > 0.f ? p0 : kAlpha * p0;
        const float s1 = p1 > 0.f ? p1 : kAlpha * p1;
        const float s2 = p2 > 0.f ? p2 : kAlpha * p2;
        const float s3 = p3 > 0.f ? p3 : kAlpha * p3;
        const float m4   = fmaxf(fmaxf(s0, s1), fmaxf(s2, s3));
        const float newM = fmaxf(m_run, m4);
        const float rs = __expf(m_run - newM);
        const float w0 = __expf(s0 - newM);
        const float w1 = __expf(s1 - newM);
        const float w2 = __expf(s2 - newM);
        const float w3 = __expf(s3 - newM);
        s_run = s_run * rs + (w0 + w1 + w2 + w3);
        acc.x = acc.x * rs + w0*b0.x + w1*b1.x + w2*b2.x + w3*b3.x;
        acc.y = acc.y * rs + w0*b0.y + w1*b1.y + w2*b2.y + w3*b3.y;
        acc.z = acc.z * rs + w0*b0.z + w1*b1.z + w2*b2.z + w3*b3.z;
        acc.w = acc.w * rs + w0*b0.w + w1*b1.w + w2*b2.w + w3*b3.w;
        m_run = newM;
    }
    for (; k < end; ++k) {
        const int d0 = csrD[k];
        const float4 b0 = emb4[(long long)d0 * 32 + g];
        float p0 = a.x*b0.x + a.y*b0.y + a.z*b0.z + a.w*b0.w;
        #pragma unroll
        for (int o = 16; o > 0; o >>= 1) p0 += __shfl_xor(p0, o);
        const float s0 = p0 > 0.f ? p0 : kAlpha * p0;
        const float newM = fmaxf(m_run, s0);
        const float rs = __expf(m_run - newM);
        const float w0 = __expf(s0 - newM);
        s_run = s_run * rs + w0;
        acc.x = acc.x * rs + w0*b0.x;
        acc.y = acc.y * rs + w0*b0.y;
        acc.z = acc.z * rs + w0*b0.z;
        acc.w = acc.w * rs + w0*b0.w;
        m_run = newM;
    }
    out4[(long long)node * 32 + g] = acc;   // unnormalized
    if (g == 0) mnode[node] = m_run;

    __shared__ float sm[256];
    __shared__ float ss[256];
    if (g == 0) { sm[grp] = m_run; ss[grp] = s_run; }
    __syncthreads();
    if (threadIdx.x == 0) {
        float M = sm[0], S = ss[0];
        #pragma unroll
        for (int i = 1; i < kNodesPerBlock; ++i) onlineMerge(M, S, sm[i], ss[i]);
        partials[blockIdx.x] = make_float2(M, S);
    }

    // last-block finalize (completion counter — no waiting, deadlock-free)
    __threadfence();
    __shared__ int isLast;
    if (threadIdx.x == 0) isLast = (atomicAdd(done2, 1) == kNodeBlocks - 1);
    __syncthreads();
    if (!isLast) return;
    __threadfence();

    float M = kNegBig, S = 0.0f;
    for (int i = threadIdx.x; i < kNodeBlocks; i += 256) {
        const float2 p = partials[i];
        onlineMerge(M, S, p.x, p.y);
    }
    sm[threadIdx.x] = M; ss[threadIdx.x] = S;
    __syncthreads();
    for (int s = 128; s > 0; s >>= 1) {
        if ((int)threadIdx.x < s) {
            float m1 = sm[threadIdx.x], s1 = ss[threadIdx.x];
            onlineMerge(m1, s1, sm[threadIdx.x + s], ss[threadIdx.x + s]);
            sm[threadIdx.x] = m1; ss[threadIdx.x] = s1;
        }
        __syncthreads();
    }
    if (threadIdx.x == 0) { wsf[kOffM] = sm[0]; wsf[kOffInvS] = 1.0f / ss[0]; }
}

// Phase 5: out = emb + out * exp(m_node - M) * invS
__global__ __launch_bounds__(256)
void epilogue_kernel(const float4* __restrict__ emb4,
                     const float* __restrict__ wsf,
                     float4* __restrict__ out4) {
    const float* mnode = wsf + kOffMnode;
    const float M    = wsf[kOffM];
    const float invS = wsf[kOffInvS];
    for (int i = blockIdx.x * blockDim.x + threadIdx.x; i < kNodes * 32;
         i += gridDim.x * blockDim.x) {
        const int node = i >> 5;
        const float scale = __expf(mnode[node] - M) * invS;
        const float4 o = out4[i];
        const float4 e = emb4[i];
        out4[i] = make_float4(e.x + scale * o.x, e.y + scale * o.y,
                              e.z + scale * o.z, e.w + scale * o.w);
    }
}

extern "C" void kernel_launch(void* const* d_in, const int* in_sizes, int n_in,
                              void* d_out, int out_size, void* d_ws, size_t ws_size,
                              hipStream_t stream) {
    const float4* emb4 = (const float4*)d_in[0];
    const int2*   rel2 = (const int2*)d_in[1];
    float4* out4 = (float4*)d_out;
    int*    wsi  = (int*)d_ws;

    int* counts  = wsi + kOffCounts;
    int* offsets = wsi + kOffOffsets;
    int* cursor  = wsi + kOffCursor;
    int* csrD    = wsi + kOffCsrD;

    // zero done counters + M/invS slots + counts in one contiguous memset
    hipMemsetAsync(wsi, 0, (size_t)(kOffCounts + kNodes) * sizeof(int), stream);
    hipLaunchKernelGGL(hist_scan_kernel, dim3(kHistGrid), dim3(kHistBlock), 0, stream,
                       rel2, wsi);
    hipLaunchKernelGGL(fillsd_kernel, dim3(1024), dim3(256), 0, stream,
                       rel2, cursor, csrD);
    hipLaunchKernelGGL(scores_fused_kernel, dim3(kNodeBlocks), dim3(256), 0, stream,
                       emb4, offsets, counts, csrD, wsi, out4);
    hipLaunchKernelGGL(epilogue_kernel, dim3(1024), dim3(256), 0, stream,
                       emb4, (const float*)wsi, out4);
}

// Round 10
// 319.001 us; speedup vs baseline: 3.9308x; 3.7217x over previous
//
#include <hip/hip_runtime.h>
#include <math.h>

constexpr int kNodes = 50000;
constexpr int kEdges = 600000;
constexpr float kAlpha = 0.2f;
constexpr float kNegBig = -1e30f;

// ws layout (4-byte units):
constexpr int kOffCounts   = 4;
constexpr int kOffOffsets  = kOffCounts + kNodes;    // 50004
constexpr int kOffCursor   = kOffOffsets + kNodes;   // 100004
constexpr int kOffCsrD     = kOffCursor + kNodes;    // 150004
constexpr int kOffMnode    = kOffCsrD + kEdges;      // 750004
constexpr int kOffPartials = kOffMnode + kNodes;     // 800004 (even -> float2 8B aligned)

constexpr int kScanThreads = 1024;
constexpr int kPerThread   = 49;                     // 1024*49 = 50176 >= 50000

constexpr int kLanes = 16;                           // lanes per node
constexpr int kNodesPerBlock = 256 / kLanes;         // 16
constexpr int kNodeBlocks = kNodes / kNodesPerBlock; // 3125 exactly

__device__ __forceinline__ void onlineMerge(float& m, float& s, float m2, float s2) {
    const float M = fmaxf(m, m2);
    s = s * __expf(m - M) + s2 * __expf(m2 - M);
    m = M;
}

__global__ __launch_bounds__(1024)
void hist_kernel(const int2* __restrict__ rel2, int* __restrict__ counts) {
    for (int e = blockIdx.x * blockDim.x + threadIdx.x; e < kEdges; e += gridDim.x * blockDim.x)
        atomicAdd(&counts[rel2[e].x], 1);
}

// Single block: exclusive scan of 50000 counts -> offsets & cursor.
__global__ __launch_bounds__(kScanThreads)
void scan_kernel(const int* __restrict__ counts,
                 int* __restrict__ offsets,
                 int* __restrict__ cursor) {
    const int base = (int)threadIdx.x * kPerThread;
    int sum = 0;
    for (int j = 0; j < kPerThread; ++j) {
        const int i = base + j;
        if (i < kNodes) sum += counts[i];
    }
    const int lane = threadIdx.x & 63;
    const int wv   = threadIdx.x >> 6;   // 16 waves
    int incl = sum;
    #pragma unroll
    for (int o = 1; o < 64; o <<= 1) {
        int v = __shfl_up(incl, o);
        if (lane >= o) incl += v;
    }
    __shared__ int wsum[16], woff[16];
    if (lane == 63) wsum[wv] = incl;
    __syncthreads();
    if (threadIdx.x == 0) {
        int run = 0;
        for (int w = 0; w < 16; ++w) { int t = wsum[w]; woff[w] = run; run += t; }
    }
    __syncthreads();
    int excl = woff[wv] + (incl - sum);
    for (int j = 0; j < kPerThread; ++j) {
        const int i = base + j;
        if (i < kNodes) {
            const int c = counts[i];
            offsets[i] = excl;
            cursor[i]  = excl;
            excl += c;
        }
    }
}

__global__ __launch_bounds__(256)
void fillsd_kernel(const int2* __restrict__ rel2,
                   int* __restrict__ cursor,
                   int* __restrict__ csrD) {
    for (int e = blockIdx.x * blockDim.x + threadIdx.x; e < kEdges; e += gridDim.x * blockDim.x) {
        const int2 sd = rel2[e];
        const int pos = atomicAdd(&cursor[sd.x], 1);
        csrD[pos] = sd.y;
    }
}

// 16 lanes per node, 8 dims (two float4) per lane. Fused dot + online softmax,
// unnormalized accumulate straight into d_out. NO fences, no cross-block deps.
__global__ __launch_bounds__(256)
void scores_fused_kernel(const float4* __restrict__ emb4,
                         const int* __restrict__ offsets,
                         const int* __restrict__ counts,
                         const int* __restrict__ csrD,
                         float* __restrict__ mnode,
                         float2* __restrict__ partials,
                         float4* __restrict__ out4) {
    const int g   = threadIdx.x & (kLanes - 1);
    const int grp = threadIdx.x >> 4;
    const int node = blockIdx.x * kNodesPerBlock + grp;   // < kNodes always

    const float4 a0 = emb4[(long long)node * 32 + 2 * g];
    const float4 a1 = emb4[(long long)node * 32 + 2 * g + 1];
    float4 accL = make_float4(0.f, 0.f, 0.f, 0.f);
    float4 accH = make_float4(0.f, 0.f, 0.f, 0.f);
    float m_run = kNegBig, s_run = 0.0f;

    const int off = offsets[node];
    const int end = off + counts[node];
    int k = off;
    for (; k + 1 < end; k += 2) {
        const int d0 = csrD[k], d1 = csrD[k + 1];
        const float4 b0L = emb4[(long long)d0 * 32 + 2 * g];
        const float4 b0H = emb4[(long long)d0 * 32 + 2 * g + 1];
        const float4 b1L = emb4[(long long)d1 * 32 + 2 * g];
        const float4 b1H = emb4[(long long)d1 * 32 + 2 * g + 1];
        float p0 = a0.x*b0L.x + a0.y*b0L.y + a0.z*b0L.z + a0.w*b0L.w
                 + a1.x*b0H.x + a1.y*b0H.y + a1.z*b0H.z + a1.w*b0H.w;
        float p1 = a0.x*b1L.x + a0.y*b1L.y + a0.z*b1L.z + a0.w*b1L.w
                 + a1.x*b1H.x + a1.y*b1H.y + a1.z*b1H.z + a1.w*b1H.w;
        #pragma unroll
        for (int o = 8; o > 0; o >>= 1) { p0 += __shfl_xor(p0, o); p1 += __shfl_xor(p1, o); }
        const float s0 = p0 > 0.f ? p0 : kAlpha * p0;
        const float s1 = p1 > 0.f ? p1 : kAlpha * p1;
        const float newM = fmaxf(m_run, fmaxf(s0, s1));
        const float rs = __expf(m_run - newM);
        const float w0 = __expf(s0 - newM);
        const float w1 = __expf(s1 - newM);
        s_run = s_run * rs + w0 + w1;
        accL.x = accL.x * rs + w0*b0L.x + w1*b1L.x;
        accL.y = accL.y * rs + w0*b0L.y + w1*b1L.y;
        accL.z = accL.z * rs + w0*b0L.z + w1*b1L.z;
        accL.w = accL.w * rs + w0*b0L.w + w1*b1L.w;
        accH.x = accH.x * rs + w0*b0H.x + w1*b1H.x;
        accH.y = accH.y * rs + w0*b0H.y + w1*b1H.y;
        accH.z = accH.z * rs + w0*b0H.z + w1*b1H.z;
        accH.w = accH.w * rs + w0*b0H.w + w1*b1H.w;
        m_run = newM;
    }
    if (k < end) {
        const int d0 = csrD[k];
        const float4 b0L = emb4[(long long)d0 * 32 + 2 * g];
        const float4 b0H = emb4[(long long)d0 * 32 + 2 * g + 1];
        float p0 = a0.x*b0L.x + a0.y*b0L.y + a0.z*b0L.z + a0.w*b0L.w
                 + a1.x*b0H.x + a1.y*b0H.y + a1.z*b0H.z + a1.w*b0H.w;
        #pragma unroll
        for (int o = 8; o > 0; o >>= 1) p0 += __shfl_xor(p0, o);
        const float s0 = p0 > 0.f ? p0 : kAlpha * p0;
        const float newM = fmaxf(m_run, s0);
        const float rs = __expf(m_run - newM);
        const float w0 = __expf(s0 - newM);
        s_run = s_run * rs + w0;
        accL.x = accL.x * rs + w0*b0L.x;
        accL.y = accL.y * rs + w0*b0L.y;
        accL.z = accL.z * rs + w0*b0L.z;
        accL.w = accL.w * rs + w0*b0L.w;
        accH.x = accH.x * rs + w0*b0H.x;
        accH.y = accH.y * rs + w0*b0H.y;
        accH.z = accH.z * rs + w0*b0H.z;
        accH.w = accH.w * rs + w0*b0H.w;
        m_run = newM;
    }
    out4[(long long)node * 32 + 2 * g]     = accL;   // unnormalized
    out4[(long long)node * 32 + 2 * g + 1] = accH;
    if (g == 0) mnode[node] = m_run;

    __shared__ float sm[kNodesPerBlock];
    __shared__ float ss[kNodesPerBlock];
    if (g == 0) { sm[grp] = m_run; ss[grp] = s_run; }
    __syncthreads();
    if (threadIdx.x == 0) {
        float M = sm[0], S = ss[0];
        #pragma unroll
        for (int i = 1; i < kNodesPerBlock; ++i) onlineMerge(M, S, sm[i], ss[i]);
        partials[blockIdx.x] = make_float2(M, S);
    }
}

// Epilogue with redundant per-block finalize: every block reduces the 3125
// partials in the SAME deterministic order -> identical (M, S) everywhere.
__global__ __launch_bounds__(256)
void epilogue_kernel(const float4* __restrict__ emb4,
                     const float* __restrict__ mnode,
                     const float2* __restrict__ partials,
                     float4* __restrict__ out4) {
    __shared__ float sm[256];
    __shared__ float ss[256];
    float Mt = kNegBig, St = 0.0f;
    for (int i = threadIdx.x; i < kNodeBlocks; i += 256) {
        const float2 p = partials[i];
        onlineMerge(Mt, St, p.x, p.y);
    }
    sm[threadIdx.x] = Mt; ss[threadIdx.x] = St;
    __syncthreads();
    for (int s = 128; s > 0; s >>= 1) {
        if ((int)threadIdx.x < s) {
            float m1 = sm[threadIdx.x], s1 = ss[threadIdx.x];
            onlineMerge(m1, s1, sm[threadIdx.x + s], ss[threadIdx.x + s]);
            sm[threadIdx.x] = m1; ss[threadIdx.x] = s1;
        }
        __syncthreads();
    }
    const float M    = sm[0];
    const float invS = 1.0f / ss[0];

    for (int i = blockIdx.x * blockDim.x + threadIdx.x; i < kNodes * 32;
         i += gridDim.x * blockDim.x) {
        const int node = i >> 5;
        const float scale = __expf(mnode[node] - M) * invS;
        const float4 o = out4[i];
        const float4 e = emb4[i];
        out4[i] = make_float4(e.x + scale * o.x, e.y + scale * o.y,
                              e.z + scale * o.z, e.w + scale * o.w);
    }
}

extern "C" void kernel_launch(void* const* d_in, const int* in_sizes, int n_in,
                              void* d_out, int out_size, void* d_ws, size_t ws_size,
                              hipStream_t stream) {
    const float4* emb4 = (const float4*)d_in[0];
    const int2*   rel2 = (const int2*)d_in[1];
    float4* out4 = (float4*)d_out;
    int*    wsi  = (int*)d_ws;
    float*  wsf  = (float*)d_ws;

    int*    counts   = wsi + kOffCounts;
    int*    offsets  = wsi + kOffOffsets;
    int*    cursor   = wsi + kOffCursor;
    int*    csrD     = wsi + kOffCsrD;
    float*  mnode    = wsf + kOffMnode;
    float2* partials = (float2*)(wsf + kOffPartials);

    hipMemsetAsync(wsi, 0, (size_t)(kOffCounts + kNodes) * sizeof(int), stream);
    hipLaunchKernelGGL(hist_kernel, dim3(586), dim3(1024), 0, stream, rel2, counts);
    hipLaunchKernelGGL(scan_kernel, dim3(1), dim3(kScanThreads), 0, stream,
                       counts, offsets, cursor);
    hipLaunchKernelGGL(fillsd_kernel, dim3(1024), dim3(256), 0, stream,
                       rel2, cursor, csrD);
    hipLaunchKernelGGL(scores_fused_kernel, dim3(kNodeBlocks), dim3(256), 0, stream,
                       emb4, offsets, counts, csrD, mnode, partials, out4);
    hipLaunchKernelGGL(epilogue_kernel, dim3(1024), dim3(256), 0, stream,
                       emb4, mnode, partials, out4);
}

// Round 11
// 231.574 us; speedup vs baseline: 5.4148x; 1.3775x over previous
//
#include <hip/hip_runtime.h>
#include <math.h>

constexpr int kNodes = 50000;
constexpr int kEdges = 600000;
constexpr float kAlpha = 0.2f;
constexpr float kNegBig = -1e30f;

// ws layout (4-byte units):
constexpr int kOffCounts   = 4;
constexpr int kOffOffsets  = kOffCounts + kNodes;    // 50004
constexpr int kOffCursor   = kOffOffsets + kNodes;   // 100004
constexpr int kOffCsrD     = kOffCursor + kNodes;    // 150004
constexpr int kOffMnode    = kOffCsrD + kEdges;      // 750004
constexpr int kOffPartials = kOffMnode + kNodes;     // 800004 (even -> float2 8B aligned)

constexpr int kScanChunk  = 1024;
constexpr int kScanBlocks = (kNodes + kScanChunk - 1) / kScanChunk; // 49

constexpr int kLanes = 16;                           // lanes per node
constexpr int kNodesPerBlock = 256 / kLanes;         // 16
constexpr int kNodeBlocks = kNodes / kNodesPerBlock; // 3125 exactly

__device__ __forceinline__ void onlineMerge(float& m, float& s, float m2, float s2) {
    const float M = fmaxf(m, m2);
    s = s * __expf(m - M) + s2 * __expf(m2 - M);
    m = M;
}

__global__ __launch_bounds__(1024)
void hist_kernel(const int2* __restrict__ rel2, int* __restrict__ counts) {
    for (int e = blockIdx.x * blockDim.x + threadIdx.x; e < kEdges; e += gridDim.x * blockDim.x)
        atomicAdd(&counts[rel2[e].x], 1);
}

// One dispatch, 49 blocks. Block b: (1) redundantly stream-sum counts[0..b*1024)
// (coalesced, L2-hot) for its base; (2) scan its own 1024-chunk with coalesced
// 4-contiguous-per-thread writes (the R6 scanC pattern).
__global__ __launch_bounds__(256)
void scan_fused_kernel(const int* __restrict__ counts,
                       int* __restrict__ offsets,
                       int* __restrict__ cursor) {
    const int chunkBase = blockIdx.x * kScanChunk;

    // phase 1: base = sum of all counts before my chunk (strided -> coalesced)
    int pre = 0;
    for (int i = threadIdx.x; i < chunkBase; i += 256) pre += counts[i];
    __shared__ int red[256];
    red[threadIdx.x] = pre;
    __syncthreads();
    for (int s = 128; s > 0; s >>= 1) {
        if ((int)threadIdx.x < s) red[threadIdx.x] += red[threadIdx.x + s];
        __syncthreads();
    }
    const int base = red[0];
    __syncthreads();

    // phase 2: exclusive scan of my 1024-chunk (4 contiguous elems per thread)
    const int lane = threadIdx.x & 63;
    const int wave = threadIdx.x >> 6;
    int c[4];
    int sum4 = 0;
    #pragma unroll
    for (int j = 0; j < 4; ++j) {
        const int i = chunkBase + 4 * (int)threadIdx.x + j;
        c[j] = (i < kNodes) ? counts[i] : 0;
        sum4 += c[j];
    }
    int incl = sum4;
    #pragma unroll
    for (int o = 1; o < 64; o <<= 1) {
        int v = __shfl_up(incl, o);
        if (lane >= o) incl += v;
    }
    __shared__ int waveSum[4];
    __shared__ int waveOff[4];
    if (lane == 63) waveSum[wave] = incl;
    __syncthreads();
    if (threadIdx.x == 0) {
        int run = 0;
        for (int w = 0; w < 4; ++w) { int t = waveSum[w]; waveOff[w] = run; run += t; }
    }
    __syncthreads();
    int excl = base + waveOff[wave] + (incl - sum4);
    #pragma unroll
    for (int j = 0; j < 4; ++j) {
        const int i = chunkBase + 4 * (int)threadIdx.x + j;
        if (i < kNodes) { offsets[i] = excl; cursor[i] = excl; }
        excl += c[j];
    }
}

__global__ __launch_bounds__(256)
void fillsd_kernel(const int2* __restrict__ rel2,
                   int* __restrict__ cursor,
                   int* __restrict__ csrD) {
    for (int e = blockIdx.x * blockDim.x + threadIdx.x; e < kEdges; e += gridDim.x * blockDim.x) {
        const int2 sd = rel2[e];
        const int pos = atomicAdd(&cursor[sd.x], 1);
        csrD[pos] = sd.y;
    }
}

// 16 lanes per node, 8 dims (two float4) per lane. Fused dot + online softmax,
// unnormalized accumulate straight into d_out. No fences, no cross-block deps.
__global__ __launch_bounds__(256)
void scores_fused_kernel(const float4* __restrict__ emb4,
                         const int* __restrict__ offsets,
                         const int* __restrict__ counts,
                         const int* __restrict__ csrD,
                         float* __restrict__ mnode,
                         float2* __restrict__ partials,
                         float4* __restrict__ out4) {
    const int g   = threadIdx.x & (kLanes - 1);
    const int grp = threadIdx.x >> 4;
    const int node = blockIdx.x * kNodesPerBlock + grp;   // < kNodes always

    const float4 a0 = emb4[(long long)node * 32 + 2 * g];
    const float4 a1 = emb4[(long long)node * 32 + 2 * g + 1];
    float4 accL = make_float4(0.f, 0.f, 0.f, 0.f);
    float4 accH = make_float4(0.f, 0.f, 0.f, 0.f);
    float m_run = kNegBig, s_run = 0.0f;

    const int off = offsets[node];
    const int end = off + counts[node];
    int k = off;
    for (; k + 1 < end; k += 2) {
        const int d0 = csrD[k], d1 = csrD[k + 1];
        const float4 b0L = emb4[(long long)d0 * 32 + 2 * g];
        const float4 b0H = emb4[(long long)d0 * 32 + 2 * g + 1];
        const float4 b1L = emb4[(long long)d1 * 32 + 2 * g];
        const float4 b1H = emb4[(long long)d1 * 32 + 2 * g + 1];
        float p0 = a0.x*b0L.x + a0.y*b0L.y + a0.z*b0L.z + a0.w*b0L.w
                 + a1.x*b0H.x + a1.y*b0H.y + a1.z*b0H.z + a1.w*b0H.w;
        float p1 = a0.x*b1L.x + a0.y*b1L.y + a0.z*b1L.z + a0.w*b1L.w
                 + a1.x*b1H.x + a1.y*b1H.y + a1.z*b1H.z + a1.w*b1H.w;
        #pragma unroll
        for (int o = 8; o > 0; o >>= 1) { p0 += __shfl_xor(p0, o); p1 += __shfl_xor(p1, o); }
        const float s0 = p0 > 0.f ? p0 : kAlpha * p0;
        const float s1 = p1 > 0.f ? p1 : kAlpha * p1;
        const float newM = fmaxf(m_run, fmaxf(s0, s1));
        const float rs = __expf(m_run - newM);
        const float w0 = __expf(s0 - newM);
        const float w1 = __expf(s1 - newM);
        s_run = s_run * rs + w0 + w1;
        accL.x = accL.x * rs + w0*b0L.x + w1*b1L.x;
        accL.y = accL.y * rs + w0*b0L.y + w1*b1L.y;
        accL.z = accL.z * rs + w0*b0L.z + w1*b1L.z;
        accL.w = accL.w * rs + w0*b0L.w + w1*b1L.w;
        accH.x = accH.x * rs + w0*b0H.x + w1*b1H.x;
        accH.y = accH.y * rs + w0*b0H.y + w1*b1H.y;
        accH.z = accH.z * rs + w0*b0H.z + w1*b1H.z;
        accH.w = accH.w * rs + w0*b0H.w + w1*b1H.w;
        m_run = newM;
    }
    if (k < end) {
        const int d0 = csrD[k];
        const float4 b0L = emb4[(long long)d0 * 32 + 2 * g];
        const float4 b0H = emb4[(long long)d0 * 32 + 2 * g + 1];
        float p0 = a0.x*b0L.x + a0.y*b0L.y + a0.z*b0L.z + a0.w*b0L.w
                 + a1.x*b0H.x + a1.y*b0H.y + a1.z*b0H.z + a1.w*b0H.w;
        #pragma unroll
        for (int o = 8; o > 0; o >>= 1) p0 += __shfl_xor(p0, o);
        const float s0 = p0 > 0.f ? p0 : kAlpha * p0;
        const float newM = fmaxf(m_run, s0);
        const float rs = __expf(m_run - newM);
        const float w0 = __expf(s0 - newM);
        s_run = s_run * rs + w0;
        accL.x = accL.x * rs + w0*b0L.x;
        accL.y = accL.y * rs + w0*b0L.y;
        accL.z = accL.z * rs + w0*b0L.z;
        accL.w = accL.w * rs + w0*b0L.w;
        accH.x = accH.x * rs + w0*b0H.x;
        accH.y = accH.y * rs + w0*b0H.y;
        accH.z = accH.z * rs + w0*b0H.z;
        accH.w = accH.w * rs + w0*b0H.w;
        m_run = newM;
    }
    out4[(long long)node * 32 + 2 * g]     = accL;   // unnormalized
    out4[(long long)node * 32 + 2 * g + 1] = accH;
    if (g == 0) mnode[node] = m_run;

    __shared__ float sm[kNodesPerBlock];
    __shared__ float ss[kNodesPerBlock];
    if (g == 0) { sm[grp] = m_run; ss[grp] = s_run; }
    __syncthreads();
    if (threadIdx.x == 0) {
        float M = sm[0], S = ss[0];
        #pragma unroll
        for (int i = 1; i < kNodesPerBlock; ++i) onlineMerge(M, S, sm[i], ss[i]);
        partials[blockIdx.x] = make_float2(M, S);
    }
}

// Epilogue with redundant per-block finalize: every block reduces the 3125
// partials in the SAME deterministic order -> identical (M, S) everywhere.
__global__ __launch_bounds__(256)
void epilogue_kernel(const float4* __restrict__ emb4,
                     const float* __restrict__ mnode,
                     const float2* __restrict__ partials,
                     float4* __restrict__ out4) {
    __shared__ float sm[256];
    __shared__ float ss[256];
    float Mt = kNegBig, St = 0.0f;
    for (int i = threadIdx.x; i < kNodeBlocks; i += 256) {
        const float2 p = partials[i];
        onlineMerge(Mt, St, p.x, p.y);
    }
    sm[threadIdx.x] = Mt; ss[threadIdx.x] = St;
    __syncthreads();
    for (int s = 128; s > 0; s >>= 1) {
        if ((int)threadIdx.x < s) {
            float m1 = sm[threadIdx.x], s1 = ss[threadIdx.x];
            onlineMerge(m1, s1, sm[threadIdx.x + s], ss[threadIdx.x + s]);
            sm[threadIdx.x] = m1; ss[threadIdx.x] = s1;
        }
        __syncthreads();
    }
    const float M    = sm[0];
    const float invS = 1.0f / ss[0];

    for (int i = blockIdx.x * blockDim.x + threadIdx.x; i < kNodes * 32;
         i += gridDim.x * blockDim.x) {
        const int node = i >> 5;
        const float scale = __expf(mnode[node] - M) * invS;
        const float4 o = out4[i];
        const float4 e = emb4[i];
        out4[i] = make_float4(e.x + scale * o.x, e.y + scale * o.y,
                              e.z + scale * o.z, e.w + scale * o.w);
    }
}

extern "C" void kernel_launch(void* const* d_in, const int* in_sizes, int n_in,
                              void* d_out, int out_size, void* d_ws, size_t ws_size,
                              hipStream_t stream) {
    const float4* emb4 = (const float4*)d_in[0];
    const int2*   rel2 = (const int2*)d_in[1];
    float4* out4 = (float4*)d_out;
    int*    wsi  = (int*)d_ws;
    float*  wsf  = (float*)d_ws;

    int*    counts   = wsi + kOffCounts;
    int*    offsets  = wsi + kOffOffsets;
    int*    cursor   = wsi + kOffCursor;
    int*    csrD     = wsi + kOffCsrD;
    float*  mnode    = wsf + kOffMnode;
    float2* partials = (float2*)(wsf + kOffPartials);

    hipMemsetAsync(wsi, 0, (size_t)(kOffCounts + kNodes) * sizeof(int), stream);
    hipLaunchKernelGGL(hist_kernel, dim3(586), dim3(1024), 0, stream, rel2, counts);
    hipLaunchKernelGGL(scan_fused_kernel, dim3(kScanBlocks), dim3(256), 0, stream,
                       counts, offsets, cursor);
    hipLaunchKernelGGL(fillsd_kernel, dim3(1024), dim3(256), 0, stream,
                       rel2, cursor, csrD);
    hipLaunchKernelGGL(scores_fused_kernel, dim3(kNodeBlocks), dim3(256), 0, stream,
                       emb4, offsets, counts, csrD, mnode, partials, out4);
    hipLaunchKernelGGL(epilogue_kernel, dim3(1024), dim3(256), 0, stream,
                       emb4, mnode, partials, out4);
}